// Round 13
// baseline (6842.869 us; speedup 1.0000x reference)
//
#include <hip/hip_runtime.h>
#include <stdint.h>
#include <string.h>

#define NTOK 8192
#define HID 2048
#define NE 32
#define DFF 768
#define NSLOT 65536
#define NB 256
#define MT 256
#define MAX_TILES 288   // 65536/256 + 32
#define NRB 1024        // router blocks, 8 tokens each
#define CVT_BLOCKS 4096

typedef unsigned short u16;
typedef unsigned int u32;

using f32x4 = __attribute__((ext_vector_type(4))) float;
using bf16x8 = __attribute__((ext_vector_type(8))) short;

static __device__ __forceinline__ u16 f2bf(float f) {
  u32 x = __float_as_uint(f);
  x += 0x7fffu + ((x >> 16) & 1u);
  return (u16)(x >> 16);
}

typedef const __attribute__((address_space(1))) unsigned int* gp_t;
typedef __attribute__((address_space(3))) unsigned int* lp_t;
static __device__ __forceinline__ void gload16(const void* g, void* l) {
  __builtin_amdgcn_global_load_lds((gp_t)g, (lp_t)l, 16, 0, 0);
}

// ---------------- merged: router (coalesced, x-in-regs) | weight convert ----------------
// blocks [0, NRB): router, token range [blockIdx.x*8, +8); wave w owns toks {2w, 2w+1}
// blocks [NRB, NRB+CVT_BLOCKS): grid-stride fp32->bf16 convert of wgu then wd
__global__ void router_convert_kernel(const float* __restrict__ x, const float* __restrict__ gw,
                                      const float* __restrict__ sim,
                                      int* __restrict__ slot_e, float* __restrict__ slot_w,
                                      u16* __restrict__ xb, int* __restrict__ blockCounts,
                                      const float* __restrict__ wgu, u16* __restrict__ wgu_b, int n1,
                                      const float* __restrict__ wd, u16* __restrict__ wd_b, int n2) {
  __shared__ float logits_s[8][NE];
  if (blockIdx.x >= NRB) {
    // ---- convert path ----
    int i = (blockIdx.x - NRB) * 256 + threadIdx.x;
    int stride = CVT_BLOCKS * 256;
    int total = n1 + n2;
    for (; i < total; i += stride) {
      const float* src = (i < n1) ? wgu : wd;
      u16* dst = (i < n1) ? wgu_b : wd_b;
      int k = (i < n1) ? i : (i - n1);
      float4 v = reinterpret_cast<const float4*>(src)[k];
      u32 lo = (u32)f2bf(v.x) | ((u32)f2bf(v.y) << 16);
      u32 hi = (u32)f2bf(v.z) | ((u32)f2bf(v.w) << 16);
      reinterpret_cast<uint2*>(dst)[k] = make_uint2(lo, hi);
    }
    return;
  }
  // ---- router path ----
  int tid = threadIdx.x;
  int wave = tid >> 6, lane = tid & 63;
  int tA = blockIdx.x * 8 + wave * 2;       // wave's two tokens
  int tB = tA + 1;
  const float4* xrA = reinterpret_cast<const float4*>(x + (size_t)tA * HID);
  const float4* xrB = reinterpret_cast<const float4*>(x + (size_t)tB * HID);
  float4 xa[8], xc[8];
#pragma unroll
  for (int j = 0; j < 8; ++j) { xa[j] = xrA[j * 64 + lane]; xc[j] = xrB[j * 64 + lane]; }
  // bf16 copy straight from registers (coalesced uint2 per lane)
  uint2* xoA = reinterpret_cast<uint2*>(xb + (size_t)tA * HID);
  uint2* xoB = reinterpret_cast<uint2*>(xb + (size_t)tB * HID);
#pragma unroll
  for (int j = 0; j < 8; ++j) {
    uint2 pA = make_uint2((u32)f2bf(xa[j].x) | ((u32)f2bf(xa[j].y) << 16),
                          (u32)f2bf(xa[j].z) | ((u32)f2bf(xa[j].w) << 16));
    uint2 pB = make_uint2((u32)f2bf(xc[j].x) | ((u32)f2bf(xc[j].y) << 16),
                          (u32)f2bf(xc[j].z) | ((u32)f2bf(xc[j].w) << 16));
    xoA[j * 64 + lane] = pA;
    xoB[j * 64 + lane] = pB;
  }
  // logits: loop experts, gw row coalesced, dot both register rows, butterfly-reduce
  for (int e = 0; e < NE; ++e) {
    const float4* gv = reinterpret_cast<const float4*>(gw + (size_t)e * HID);
    float aA = 0.f, aB = 0.f;
#pragma unroll
    for (int j = 0; j < 8; ++j) {
      float4 gg = gv[j * 64 + lane];
      aA = fmaf(xa[j].x, gg.x, aA); aA = fmaf(xa[j].y, gg.y, aA);
      aA = fmaf(xa[j].z, gg.z, aA); aA = fmaf(xa[j].w, gg.w, aA);
      aB = fmaf(xc[j].x, gg.x, aB); aB = fmaf(xc[j].y, gg.y, aB);
      aB = fmaf(xc[j].z, gg.z, aB); aB = fmaf(xc[j].w, gg.w, aB);
    }
#pragma unroll
    for (int off = 32; off; off >>= 1) { aA += __shfl_xor(aA, off); aB += __shfl_xor(aB, off); }
    if (lane == 0) { logits_s[wave * 2][e] = aA; logits_s[wave * 2 + 1][e] = aB; }
  }
  __syncthreads();
  // top-8 + reroute: thread (tok = tid>>5, e = tid&31), 32-lane butterfly argmax
  int tok = tid >> 5, e = tid & 31;
  float s = logits_s[tok][e];
  float cur = s;
  int myi = e;
  int idx[8]; float lv[8];
#pragma unroll
  for (int k = 0; k < 8; ++k) {
    float bv = cur; int bi = myi;
#pragma unroll
    for (int off = 16; off; off >>= 1) {
      float ov = __shfl_xor(bv, off);
      int oi = __shfl_xor(bi, off);
      if (ov > bv || (ov == bv && oi < bi)) { bv = ov; bi = oi; }
    }
    idx[k] = bi; lv[k] = bv;          // uniform across the half-wave
    if (myi == bi) cur = -3.4e38f;    // mask winner
  }
  float w[8]; float ssum = 0.f;
#pragma unroll
  for (int k = 0; k < 8; ++k) { w[k] = __expf(lv[k] - lv[0]); ssum += w[k]; }
  float inv = 1.f / ssum;
  int t = blockIdx.x * 8 + tok;
  int base = t * 8;
  if (e < 4) {
    slot_e[base + e] = idx[e];
    slot_w[base + e] = w[e] * inv;
    int sj = idx[4 + e];
    float best = -2.f; int bsel = idx[0];
#pragma unroll
    for (int i = 0; i < 4; ++i) {
      int pe = idx[i];
      float sv = sim[sj * NE + pe];
      bool ok = sv > best;              // strict > == argmax first-max
      best = ok ? sv : best;
      bsel = ok ? pe : bsel;
    }
    int ns = (best < 0.5f) ? sj : bsel;
    slot_e[base + 4 + e] = ns;
    slot_w[base + 4 + e] = w[4 + e] * inv;
    atomicAdd(&blockCounts[idx[e] * NB + (t >> 5)], 1);
    atomicAdd(&blockCounts[ns * NB + (t >> 5)], 1);
  }
}

// ---------------- counting sort: scan / place ----------------
__global__ void scan_kernel(const int* __restrict__ blockCounts, int* __restrict__ startEB,
                            int* __restrict__ tile_e, int* __restrict__ tile_row0,
                            int* __restrict__ tile_cnt, int* __restrict__ tileCount) {
  __shared__ int totals[NE];
  __shared__ int bases[NE];
  int t = threadIdx.x;
  if (t < NE) {
    int run = 0;
    for (int b = 0; b < NB; ++b) run += blockCounts[t * NB + b];
    totals[t] = run;
  }
  __syncthreads();
  if (t == 0) {
    int base = 0, nt = 0;
    for (int e = 0; e < NE; ++e) {
      bases[e] = base;
      int tot = totals[e];
      for (int i = 0; i < tot; i += MT) {
        tile_e[nt] = e;
        tile_row0[nt] = base + i;
        tile_cnt[nt] = (tot - i < MT) ? (tot - i) : MT;
        ++nt;
      }
      base += tot;
    }
    *tileCount = nt;
  }
  __syncthreads();
  if (t < NE) {
    int run = bases[t];
    for (int b = 0; b < NB; ++b) {
      startEB[t * NB + b] = run;
      run += blockCounts[t * NB + b];
    }
  }
}

__global__ void place_kernel(const int* __restrict__ slot_e, const float* __restrict__ slot_w,
                             const int* __restrict__ startEB,
                             int* __restrict__ perm_token, float* __restrict__ perm_w,
                             int* __restrict__ inv) {
  __shared__ int se[256];
  __shared__ float sw[256];
  int b = blockIdx.x;
  for (int i = threadIdx.x; i < 256; i += 64) {
    se[i] = slot_e[b * 256 + i];
    sw[i] = slot_w[b * 256 + i];
  }
  __syncthreads();
  int e = threadIdx.x;
  if (e < NE) {
    int pos = startEB[e * NB + b];
    for (int i = 0; i < 256; ++i) {
      if (se[i] == e) {
        perm_token[pos] = (b * 256 + i) >> 3;
        perm_w[pos] = sw[i];
        inv[b * 256 + i] = pos;
        ++pos;
      }
    }
  }
}

// ---------------- 2-region 256x256 grouped GEMM machinery ----------------
// 2 LDS regions (BK=32 each, 64KB total -> 2 blocks/CU). Per window: drain lgkm,
// vmcnt(0) (stage had a full window in flight), barrier, issue next stage, then
// two 16-MFMA clusters. Inter-block TLP overlaps read bursts with MFMA.

#define GUMM(AR, M_)                                                                   \
  acc[M_][0] = __builtin_amdgcn_mfma_f32_16x16x32_bf16(AR, b0, acc[M_][0], 0, 0, 0);   \
  acc[M_][1] = __builtin_amdgcn_mfma_f32_16x16x32_bf16(AR, b1, acc[M_][1], 0, 0, 0);   \
  acc[M_][2] = __builtin_amdgcn_mfma_f32_16x16x32_bf16(AR, b2, acc[M_][2], 0, 0, 0);   \
  acc[M_][3] = __builtin_amdgcn_mfma_f32_16x16x32_bf16(AR, b3, acc[M_][3], 0, 0, 0);

#define GWIN(BUF, ST)                                                                  \
  do {                                                                                 \
    asm volatile("s_waitcnt lgkmcnt(0)" ::: "memory");                                 \
    __builtin_amdgcn_sched_barrier(0);                                                 \
    asm volatile("s_waitcnt vmcnt(0)" ::: "memory");                                   \
    __builtin_amdgcn_s_barrier();                                                      \
    ST;                                                                                \
    const u16* Ap_ = &SA[BUF][abase];                                                  \
    const u16* Bp_ = &SB[BUF][0];                                                      \
    bf16x8 a0_ = *(const bf16x8*)(Ap_);                                                \
    bf16x8 a1_ = *(const bf16x8*)(Ap_ + 512);                                          \
    bf16x8 a2_ = *(const bf16x8*)(Ap_ + 1024);                                         \
    bf16x8 a3_ = *(const bf16x8*)(Ap_ + 1536);                                         \
    bf16x8 b0 = *(const bf16x8*)(Bp_ + boff0);                                         \
    bf16x8 b1 = *(const bf16x8*)(Bp_ + boff1);                                         \
    bf16x8 b2 = *(const bf16x8*)(Bp_ + boff2);                                         \
    bf16x8 b3 = *(const bf16x8*)(Bp_ + boff3);                                         \
    __builtin_amdgcn_s_setprio(1);                                                     \
    GUMM(a0_, 0) GUMM(a1_, 1) GUMM(a2_, 2) GUMM(a3_, 3)                                \
    __builtin_amdgcn_s_setprio(0);                                                     \
    bf16x8 c0_ = *(const bf16x8*)(Ap_ + 2048);                                         \
    bf16x8 c1_ = *(const bf16x8*)(Ap_ + 2560);                                         \
    bf16x8 c2_ = *(const bf16x8*)(Ap_ + 3072);                                         \
    bf16x8 c3_ = *(const bf16x8*)(Ap_ + 3584);                                         \
    __builtin_amdgcn_s_setprio(1);                                                     \
    GUMM(c0_, 4) GUMM(c1_, 5) GUMM(c2_, 6) GUMM(c3_, 7)                                \
    __builtin_amdgcn_s_setprio(0);                                                     \
  } while (0)

// ---------------- gate_up GEMM: 256 slots x (128 gate + 128 up cols) ----------------
__global__ __launch_bounds__(512, 4) void gu_fast(
    const u16* __restrict__ xb, const u16* __restrict__ wgub,
    const int* __restrict__ perm_token,
    const int* __restrict__ tile_e, const int* __restrict__ tile_row0,
    const int* __restrict__ tile_cnt, const int* __restrict__ tileCount,
    u16* __restrict__ h_perm) {
  // XCD clustering: flat%8 = XCD; give each XCD a contiguous 36-tile chunk.
  int flat = blockIdx.x + blockIdx.y * 6;       // NWG = 6*288 = 1728, %8 == 0
  int xcd = flat & 7;
  int j = flat >> 3;                            // 0..215
  int tile = xcd * 36 + j / 6;
  int n0g = (j % 6) * 128;
  if (tile >= *tileCount) return;
  int e = tile_e[tile], row0 = tile_row0[tile], cnt = tile_cnt[tile];
  __shared__ __align__(16) u16 SA[2][8192];   // [region][256 rows x 32 K]
  __shared__ __align__(16) u16 SB[2][8192];   // rows 0-127 gate, 128-255 up
  __shared__ int toks[256];
  int tid = threadIdx.x;
  if (tid < 256) {
    int idx = row0 + tid;
    if (idx > NSLOT - 1) idx = NSLOT - 1;
    toks[tid] = perm_token[idx];
  }
  __syncthreads();
  int wave = tid >> 6, lane = tid & 63;
  int wr = wave >> 2, wc = wave & 3;
  int lr = lane & 15, lk = lane >> 4;
  int sr0 = tid >> 2;                       // rows 0..127 (+128 for 2nd load)
  int sc0 = (tid & 3) ^ ((tid >> 3) & 3);   // pre-swizzled K-chunk
  const u16* gA0 = xb + (size_t)toks[sr0] * HID + sc0 * 8;
  const u16* gA1 = xb + (size_t)toks[128 + sr0] * HID + sc0 * 8;
  const u16* wgb = wgub + (size_t)e * (2 * DFF) * HID;
  const u16* gB0 = wgb + (size_t)(n0g + sr0) * HID + sc0 * 8;          // gate row
  const u16* gB1 = wgb + (size_t)(DFF + n0g + sr0) * HID + sc0 * 8;    // up row
  int d0 = tid * 8, d1 = 4096 + tid * 8;    // linear LDS dests (u16 units)

  int slot8 = (lk ^ ((lr >> 1) & 3)) * 8;
  int abase = (wr * 128 + lr) * 32 + slot8;
  int boff0 = (wc * 32 + 0 * 16 + lr) * 32 + slot8;          // gate
  int boff1 = (wc * 32 + 1 * 16 + lr) * 32 + slot8;          // gate
  int boff2 = (128 + wc * 32 + 0 * 16 + lr) * 32 + slot8;    // up
  int boff3 = (128 + wc * 32 + 1 * 16 + lr) * 32 + slot8;    // up

  f32x4 acc[8][4];
  f32x4 zero = {0.f, 0.f, 0.f, 0.f};
#pragma unroll
  for (int m = 0; m < 8; ++m)
#pragma unroll
    for (int n = 0; n < 4; ++n) acc[m][n] = zero;

#define GU_ST(BUF, KOFF) do { \
    gload16(gA0 + (KOFF), &SA[BUF][d0]); \
    gload16(gA1 + (KOFF), &SA[BUF][d1]); \
    gload16(gB0 + (KOFF), &SB[BUF][d0]); \
    gload16(gB1 + (KOFF), &SB[BUF][d1]); } while (0)

  GU_ST(0, 0);                  // prologue: window 0 staged
  const int NW = HID / 32;      // 64 windows
  for (int w2 = 0; w2 < NW / 2; ++w2) {
    int k1 = (2 * w2 + 1) * 32;
    int k2 = (2 * w2 + 2) * 32;
    GWIN(0, GU_ST(1, k1));
    GWIN(1, if (k2 < HID) GU_ST(0, k2));
  }

  // epilogue: h = silu(g) * u ; acc[m][0,1]=gate cols, acc[m][2,3]=up cols
#pragma unroll
  for (int m = 0; m < 8; ++m)
#pragma unroll
    for (int i = 0; i < 4; ++i) {
      int row = wr * 128 + m * 16 + lk * 4 + i;
      if (row < cnt) {
#pragma unroll
        for (int nf = 0; nf < 2; ++nf) {
          int col = n0g + wc * 32 + nf * 16 + lr;
          float g = acc[m][nf][i], u = acc[m][nf + 2][i];
          float h = g / (1.f + __expf(-g)) * u;
          h_perm[(size_t)(row0 + row) * DFF + col] = f2bf(h);
        }
      }
    }
#undef GU_ST
}

// ---------------- down GEMM: 256 slots x 256 hid cols -> yp (fp16) ----------------
__global__ __launch_bounds__(512, 4) void down_fast(
    const u16* __restrict__ h_perm, const u16* __restrict__ wdb,
    const float* __restrict__ perm_w,
    const int* __restrict__ tile_e, const int* __restrict__ tile_row0,
    const int* __restrict__ tile_cnt, const int* __restrict__ tileCount,
    _Float16* __restrict__ yp) {
  int flat = blockIdx.x + blockIdx.y * 8;       // NWG = 8*288 = 2304, %8 == 0
  int xcd = flat & 7;
  int j = flat >> 3;                            // 0..287
  int tile = xcd * 36 + j / 8;
  int n0 = (j % 8) * 256;
  if (tile >= *tileCount) return;
  int e = tile_e[tile], row0 = tile_row0[tile], cnt = tile_cnt[tile];
  __shared__ __align__(16) u16 SA[2][8192];
  __shared__ __align__(16) u16 SB[2][8192];
  __shared__ float wts[256];
  int tid = threadIdx.x;
  if (tid < 256) {
    int idx = row0 + tid;
    if (idx > NSLOT - 1) idx = NSLOT - 1;
    wts[tid] = perm_w[idx];
  }
  __syncthreads();
  int wave = tid >> 6, lane = tid & 63;
  int wr = wave >> 2, wc = wave & 3;
  int lr = lane & 15, lk = lane >> 4;
  int sr0 = tid >> 2;
  int sc0 = (tid & 3) ^ ((tid >> 3) & 3);
  int ia0 = row0 + sr0;       if (ia0 > NSLOT - 1) ia0 = NSLOT - 1;
  int ia1 = row0 + 128 + sr0; if (ia1 > NSLOT - 1) ia1 = NSLOT - 1;
  const u16* gA0 = h_perm + (size_t)ia0 * DFF + sc0 * 8;
  const u16* gA1 = h_perm + (size_t)ia1 * DFF + sc0 * 8;
  const u16* wb = wdb + (size_t)e * HID * DFF;
  const u16* gB0 = wb + (size_t)(n0 + sr0) * DFF + sc0 * 8;
  const u16* gB1 = wb + (size_t)(n0 + 128 + sr0) * DFF + sc0 * 8;
  int d0 = tid * 8, d1 = 4096 + tid * 8;

  int slot8 = (lk ^ ((lr >> 1) & 3)) * 8;
  int abase = (wr * 128 + lr) * 32 + slot8;
  int boff0 = (wc * 64 + 0 * 16 + lr) * 32 + slot8;
  int boff1 = (wc * 64 + 1 * 16 + lr) * 32 + slot8;
  int boff2 = (wc * 64 + 2 * 16 + lr) * 32 + slot8;
  int boff3 = (wc * 64 + 3 * 16 + lr) * 32 + slot8;

  f32x4 acc[8][4];
  f32x4 zero = {0.f, 0.f, 0.f, 0.f};
#pragma unroll
  for (int m = 0; m < 8; ++m)
#pragma unroll
    for (int n = 0; n < 4; ++n) acc[m][n] = zero;

#define DN_ST(BUF, KOFF) do { \
    gload16(gA0 + (KOFF), &SA[BUF][d0]); \
    gload16(gA1 + (KOFF), &SA[BUF][d1]); \
    gload16(gB0 + (KOFF), &SB[BUF][d0]); \
    gload16(gB1 + (KOFF), &SB[BUF][d1]); } while (0)

  DN_ST(0, 0);
  const int NW = DFF / 32;      // 24 windows
  for (int w2 = 0; w2 < NW / 2; ++w2) {
    int k1 = (2 * w2 + 1) * 32;
    int k2 = (2 * w2 + 2) * 32;
    GWIN(0, DN_ST(1, k1));
    GWIN(1, if (k2 < DFF) DN_ST(0, k2));
  }

#pragma unroll
  for (int m = 0; m < 8; ++m)
#pragma unroll
    for (int i = 0; i < 4; ++i) {
      int row = wr * 128 + m * 16 + lk * 4 + i;
      if (row < cnt) {
        float wt = wts[row];
#pragma unroll
        for (int nf = 0; nf < 4; ++nf) {
          int col = n0 + wc * 64 + nf * 16 + lr;
          yp[(size_t)(row0 + row) * HID + col] = (_Float16)(acc[m][nf][i] * wt);
        }
      }
    }
#undef DN_ST
}

// ---------------- per-token gather-reduce of 8 slots ----------------
__global__ void reduce_kernel(const _Float16* __restrict__ yp, const int* __restrict__ inv,
                              float* __restrict__ y) {
  int t = blockIdx.x;
  __shared__ int pos[8];
  if (threadIdx.x < 8) pos[threadIdx.x] = inv[t * 8 + threadIdx.x];
  __syncthreads();
  int c = threadIdx.x * 8;
  float s[8] = {0.f, 0.f, 0.f, 0.f, 0.f, 0.f, 0.f, 0.f};
#pragma unroll
  for (int j = 0; j < 8; ++j) {
    uint4 v = *reinterpret_cast<const uint4*>(yp + (size_t)pos[j] * HID + c);
    const u16* p = reinterpret_cast<const u16*>(&v);
#pragma unroll
    for (int k = 0; k < 8; ++k) {
      _Float16 h;
      u16 us = p[k];
      __builtin_memcpy(&h, &us, 2);
      s[k] += (float)h;
    }
  }
  float* yo = y + (size_t)t * HID + c;
  float4 o0 = {s[0], s[1], s[2], s[3]};
  float4 o1 = {s[4], s[5], s[6], s[7]};
  *reinterpret_cast<float4*>(yo) = o0;
  *reinterpret_cast<float4*>(yo + 4) = o1;
}

extern "C" void kernel_launch(void* const* d_in, const int* in_sizes, int n_in,
                              void* d_out, int out_size, void* d_ws, size_t ws_size,
                              hipStream_t stream) {
  const float* x = (const float*)d_in[0];
  const float* gw = (const float*)d_in[1];
  const float* wgu = (const float*)d_in[2];
  const float* wd = (const float*)d_in[3];
  const float* sim = (const float*)d_in[4];
  float* y = (float*)d_out;

  char* ws = (char*)d_ws;
  size_t off = 0;
  auto alloc = [&](size_t bytes) {
    char* p = ws + off;
    off += (bytes + 255) & ~(size_t)255;
    return p;
  };
  u16* xb = (u16*)alloc((size_t)NTOK * HID * 2);
  u16* h_perm = (u16*)alloc((size_t)NSLOT * DFF * 2);
  int* slot_e = (int*)alloc(NSLOT * 4);
  float* slot_w = (float*)alloc(NSLOT * 4);
  int* perm_token = (int*)alloc(NSLOT * 4);
  float* perm_w = (float*)alloc(NSLOT * 4);
  int* inv = (int*)alloc(NSLOT * 4);
  int* blockCounts = (int*)alloc(NE * NB * 4);
  int* startEB = (int*)alloc(NE * NB * 4);
  int* tile_e = (int*)alloc(MAX_TILES * 4);
  int* tile_row0 = (int*)alloc(MAX_TILES * 4);
  int* tile_cnt = (int*)alloc(MAX_TILES * 4);
  int* tileCount = (int*)alloc(4);

  // bf16 weights + fp16 per-slot down output (yp aliases wgu_b region)
  size_t wgu_elems = (size_t)NE * 2 * DFF * HID;
  size_t wd_elems = (size_t)NE * HID * DFF;
  size_t region_bytes = (size_t)NSLOT * HID * 2;  // yp (268MB) > wgu_b (201MB)
  u16* wd_b = (u16*)alloc(wd_elems * 2);
  char* region = alloc(region_bytes);
  u16* wgu_b = (u16*)region;
  _Float16* yp = (_Float16*)region;
  if (off > ws_size) return;  // insufficient workspace: fail loudly

  hipMemsetAsync(blockCounts, 0, NE * NB * 4, stream);
  router_convert_kernel<<<NRB + CVT_BLOCKS, 256, 0, stream>>>(
      x, gw, sim, slot_e, slot_w, xb, blockCounts,
      wgu, wgu_b, (int)(wgu_elems / 4), wd, wd_b, (int)(wd_elems / 4));
  scan_kernel<<<1, 64, 0, stream>>>(blockCounts, startEB, tile_e, tile_row0, tile_cnt, tileCount);
  place_kernel<<<NB, 64, 0, stream>>>(slot_e, slot_w, startEB, perm_token, perm_w, inv);

  gu_fast<<<dim3(DFF / 128, MAX_TILES), 512, 0, stream>>>(
      xb, wgu_b, perm_token, tile_e, tile_row0, tile_cnt, tileCount, h_perm);
  down_fast<<<dim3(HID / 256, MAX_TILES), 512, 0, stream>>>(
      h_perm, wd_b, perm_w, tile_e, tile_row0, tile_cnt, tileCount, yp);
  reduce_kernel<<<NTOK, 256, 0, stream>>>(yp, inv, y);
}

// Round 14
// 1086.395 us; speedup vs baseline: 6.2987x; 6.2987x over previous
//
#include <hip/hip_runtime.h>
#include <stdint.h>
#include <string.h>

#define NTOK 8192
#define HID 2048
#define NE 32
#define DFF 768
#define NSLOT 65536
#define NB 256
#define MT 256
#define MAX_TILES 288   // 65536/256 + 32
#define NRB 1024        // router blocks, 8 tokens each
#define CVT_BLOCKS 4096

typedef unsigned short u16;
typedef unsigned int u32;

using f32x4 = __attribute__((ext_vector_type(4))) float;
using bf16x8 = __attribute__((ext_vector_type(8))) short;

static __device__ __forceinline__ u16 f2bf(float f) {
  u32 x = __float_as_uint(f);
  x += 0x7fffu + ((x >> 16) & 1u);
  return (u16)(x >> 16);
}

typedef const __attribute__((address_space(1))) unsigned int* gp_t;
typedef __attribute__((address_space(3))) unsigned int* lp_t;
static __device__ __forceinline__ void gload16(const void* g, void* l) {
  __builtin_amdgcn_global_load_lds((gp_t)g, (lp_t)l, 16, 0, 0);
}

// ---------------- merged: router (coalesced, x-in-regs) | weight convert ----------------
// blocks [0, NRB): router, token range [blockIdx.x*8, +8); wave w owns toks {2w, 2w+1}
// blocks [NRB, NRB+CVT_BLOCKS): grid-stride fp32->bf16 convert of wgu then wd
__global__ void router_convert_kernel(const float* __restrict__ x, const float* __restrict__ gw,
                                      const float* __restrict__ sim,
                                      int* __restrict__ slot_e, float* __restrict__ slot_w,
                                      u16* __restrict__ xb, int* __restrict__ blockCounts,
                                      const float* __restrict__ wgu, u16* __restrict__ wgu_b, int n1,
                                      const float* __restrict__ wd, u16* __restrict__ wd_b, int n2) {
  __shared__ float logits_s[8][NE];
  if (blockIdx.x >= NRB) {
    // ---- convert path ----
    int i = (blockIdx.x - NRB) * 256 + threadIdx.x;
    int stride = CVT_BLOCKS * 256;
    int total = n1 + n2;
    for (; i < total; i += stride) {
      const float* src = (i < n1) ? wgu : wd;
      u16* dst = (i < n1) ? wgu_b : wd_b;
      int k = (i < n1) ? i : (i - n1);
      float4 v = reinterpret_cast<const float4*>(src)[k];
      u32 lo = (u32)f2bf(v.x) | ((u32)f2bf(v.y) << 16);
      u32 hi = (u32)f2bf(v.z) | ((u32)f2bf(v.w) << 16);
      reinterpret_cast<uint2*>(dst)[k] = make_uint2(lo, hi);
    }
    return;
  }
  // ---- router path ----
  int tid = threadIdx.x;
  int wave = tid >> 6, lane = tid & 63;
  int tA = blockIdx.x * 8 + wave * 2;       // wave's two tokens
  int tB = tA + 1;
  const float4* xrA = reinterpret_cast<const float4*>(x + (size_t)tA * HID);
  const float4* xrB = reinterpret_cast<const float4*>(x + (size_t)tB * HID);
  float4 xa[8], xc[8];
#pragma unroll
  for (int j = 0; j < 8; ++j) { xa[j] = xrA[j * 64 + lane]; xc[j] = xrB[j * 64 + lane]; }
  // bf16 copy straight from registers (coalesced uint2 per lane)
  uint2* xoA = reinterpret_cast<uint2*>(xb + (size_t)tA * HID);
  uint2* xoB = reinterpret_cast<uint2*>(xb + (size_t)tB * HID);
#pragma unroll
  for (int j = 0; j < 8; ++j) {
    uint2 pA = make_uint2((u32)f2bf(xa[j].x) | ((u32)f2bf(xa[j].y) << 16),
                          (u32)f2bf(xa[j].z) | ((u32)f2bf(xa[j].w) << 16));
    uint2 pB = make_uint2((u32)f2bf(xc[j].x) | ((u32)f2bf(xc[j].y) << 16),
                          (u32)f2bf(xc[j].z) | ((u32)f2bf(xc[j].w) << 16));
    xoA[j * 64 + lane] = pA;
    xoB[j * 64 + lane] = pB;
  }
  // logits: loop experts, gw row coalesced, dot both register rows, butterfly-reduce
  for (int e = 0; e < NE; ++e) {
    const float4* gv = reinterpret_cast<const float4*>(gw + (size_t)e * HID);
    float aA = 0.f, aB = 0.f;
#pragma unroll
    for (int j = 0; j < 8; ++j) {
      float4 gg = gv[j * 64 + lane];
      aA = fmaf(xa[j].x, gg.x, aA); aA = fmaf(xa[j].y, gg.y, aA);
      aA = fmaf(xa[j].z, gg.z, aA); aA = fmaf(xa[j].w, gg.w, aA);
      aB = fmaf(xc[j].x, gg.x, aB); aB = fmaf(xc[j].y, gg.y, aB);
      aB = fmaf(xc[j].z, gg.z, aB); aB = fmaf(xc[j].w, gg.w, aB);
    }
#pragma unroll
    for (int off = 32; off; off >>= 1) { aA += __shfl_xor(aA, off); aB += __shfl_xor(aB, off); }
    if (lane == 0) { logits_s[wave * 2][e] = aA; logits_s[wave * 2 + 1][e] = aB; }
  }
  __syncthreads();
  // top-8 + reroute: thread (tok = tid>>5, e = tid&31), 32-lane butterfly argmax
  int tok = tid >> 5, e = tid & 31;
  float s = logits_s[tok][e];
  float cur = s;
  int myi = e;
  int idx[8]; float lv[8];
#pragma unroll
  for (int k = 0; k < 8; ++k) {
    float bv = cur; int bi = myi;
#pragma unroll
    for (int off = 16; off; off >>= 1) {
      float ov = __shfl_xor(bv, off);
      int oi = __shfl_xor(bi, off);
      if (ov > bv || (ov == bv && oi < bi)) { bv = ov; bi = oi; }
    }
    idx[k] = bi; lv[k] = bv;          // uniform across the half-wave
    if (myi == bi) cur = -3.4e38f;    // mask winner
  }
  float w[8]; float ssum = 0.f;
#pragma unroll
  for (int k = 0; k < 8; ++k) { w[k] = __expf(lv[k] - lv[0]); ssum += w[k]; }
  float inv = 1.f / ssum;
  int t = blockIdx.x * 8 + tok;
  int base = t * 8;
  if (e < 4) {
    slot_e[base + e] = idx[e];
    slot_w[base + e] = w[e] * inv;
    int sj = idx[4 + e];
    float best = -2.f; int bsel = idx[0];
#pragma unroll
    for (int i = 0; i < 4; ++i) {
      int pe = idx[i];
      float sv = sim[sj * NE + pe];
      bool ok = sv > best;              // strict > == argmax first-max
      best = ok ? sv : best;
      bsel = ok ? pe : bsel;
    }
    int ns = (best < 0.5f) ? sj : bsel;
    slot_e[base + 4 + e] = ns;
    slot_w[base + 4 + e] = w[4 + e] * inv;
    atomicAdd(&blockCounts[idx[e] * NB + (t >> 5)], 1);
    atomicAdd(&blockCounts[ns * NB + (t >> 5)], 1);
  }
}

// ---------------- counting sort: scan / place ----------------
__global__ void scan_kernel(const int* __restrict__ blockCounts, int* __restrict__ startEB,
                            int* __restrict__ tile_e, int* __restrict__ tile_row0,
                            int* __restrict__ tile_cnt, int* __restrict__ tileCount) {
  __shared__ int totals[NE];
  __shared__ int bases[NE];
  int t = threadIdx.x;
  if (t < NE) {
    int run = 0;
    for (int b = 0; b < NB; ++b) run += blockCounts[t * NB + b];
    totals[t] = run;
  }
  __syncthreads();
  if (t == 0) {
    int base = 0, nt = 0;
    for (int e = 0; e < NE; ++e) {
      bases[e] = base;
      int tot = totals[e];
      for (int i = 0; i < tot; i += MT) {
        tile_e[nt] = e;
        tile_row0[nt] = base + i;
        tile_cnt[nt] = (tot - i < MT) ? (tot - i) : MT;
        ++nt;
      }
      base += tot;
    }
    *tileCount = nt;
  }
  __syncthreads();
  if (t < NE) {
    int run = bases[t];
    for (int b = 0; b < NB; ++b) {
      startEB[t * NB + b] = run;
      run += blockCounts[t * NB + b];
    }
  }
}

__global__ void place_kernel(const int* __restrict__ slot_e, const float* __restrict__ slot_w,
                             const int* __restrict__ startEB,
                             int* __restrict__ perm_token, float* __restrict__ perm_w,
                             int* __restrict__ inv) {
  __shared__ int se[256];
  __shared__ float sw[256];
  int b = blockIdx.x;
  for (int i = threadIdx.x; i < 256; i += 64) {
    se[i] = slot_e[b * 256 + i];
    sw[i] = slot_w[b * 256 + i];
  }
  __syncthreads();
  int e = threadIdx.x;
  if (e < NE) {
    int pos = startEB[e * NB + b];
    for (int i = 0; i < 256; ++i) {
      if (se[i] == e) {
        perm_token[pos] = (b * 256 + i) >> 3;
        perm_w[pos] = sw[i];
        inv[b * 256 + i] = pos;
        ++pos;
      }
    }
  }
}

// ---------------- 2-region 256x256 grouped GEMM machinery ----------------
// 2 LDS regions (BK=32 each, 64KB total -> 2 blocks/CU via LDS+VGPR, not forced).
// Per window: drain lgkm, vmcnt(0), barrier, issue next stage, two 16-MFMA clusters.

#define GUMM(AR, M_)                                                                   \
  acc[M_][0] = __builtin_amdgcn_mfma_f32_16x16x32_bf16(AR, b0, acc[M_][0], 0, 0, 0);   \
  acc[M_][1] = __builtin_amdgcn_mfma_f32_16x16x32_bf16(AR, b1, acc[M_][1], 0, 0, 0);   \
  acc[M_][2] = __builtin_amdgcn_mfma_f32_16x16x32_bf16(AR, b2, acc[M_][2], 0, 0, 0);   \
  acc[M_][3] = __builtin_amdgcn_mfma_f32_16x16x32_bf16(AR, b3, acc[M_][3], 0, 0, 0);

#define GWIN(BUF, ST)                                                                  \
  do {                                                                                 \
    asm volatile("s_waitcnt lgkmcnt(0)" ::: "memory");                                 \
    __builtin_amdgcn_sched_barrier(0);                                                 \
    asm volatile("s_waitcnt vmcnt(0)" ::: "memory");                                   \
    __builtin_amdgcn_s_barrier();                                                      \
    ST;                                                                                \
    const u16* Ap_ = &SA[BUF][abase];                                                  \
    const u16* Bp_ = &SB[BUF][0];                                                      \
    bf16x8 a0_ = *(const bf16x8*)(Ap_);                                                \
    bf16x8 a1_ = *(const bf16x8*)(Ap_ + 512);                                          \
    bf16x8 a2_ = *(const bf16x8*)(Ap_ + 1024);                                         \
    bf16x8 a3_ = *(const bf16x8*)(Ap_ + 1536);                                         \
    bf16x8 b0 = *(const bf16x8*)(Bp_ + boff0);                                         \
    bf16x8 b1 = *(const bf16x8*)(Bp_ + boff1);                                         \
    bf16x8 b2 = *(const bf16x8*)(Bp_ + boff2);                                         \
    bf16x8 b3 = *(const bf16x8*)(Bp_ + boff3);                                         \
    __builtin_amdgcn_s_setprio(1);                                                     \
    GUMM(a0_, 0) GUMM(a1_, 1) GUMM(a2_, 2) GUMM(a3_, 3)                                \
    __builtin_amdgcn_s_setprio(0);                                                     \
    bf16x8 c0_ = *(const bf16x8*)(Ap_ + 2048);                                         \
    bf16x8 c1_ = *(const bf16x8*)(Ap_ + 2560);                                         \
    bf16x8 c2_ = *(const bf16x8*)(Ap_ + 3072);                                         \
    bf16x8 c3_ = *(const bf16x8*)(Ap_ + 3584);                                         \
    __builtin_amdgcn_s_setprio(1);                                                     \
    GUMM(c0_, 4) GUMM(c1_, 5) GUMM(c2_, 6) GUMM(c3_, 7)                                \
    __builtin_amdgcn_s_setprio(0);                                                     \
  } while (0)

// ---------------- gate_up GEMM: 256 slots x (128 gate + 128 up cols) ----------------
__global__ __launch_bounds__(512, 2) void gu_fast(
    const u16* __restrict__ xb, const u16* __restrict__ wgub,
    const int* __restrict__ perm_token,
    const int* __restrict__ tile_e, const int* __restrict__ tile_row0,
    const int* __restrict__ tile_cnt, const int* __restrict__ tileCount,
    u16* __restrict__ h_perm) {
  // XCD clustering: flat%8 = XCD; give each XCD a contiguous 36-tile chunk.
  int flat = blockIdx.x + blockIdx.y * 6;       // NWG = 6*288 = 1728, %8 == 0
  int xcd = flat & 7;
  int j = flat >> 3;                            // 0..215
  int tile = xcd * 36 + j / 6;
  int n0g = (j % 6) * 128;
  if (tile >= *tileCount) return;
  int e = tile_e[tile], row0 = tile_row0[tile], cnt = tile_cnt[tile];
  __shared__ __align__(16) u16 SA[2][8192];   // [region][256 rows x 32 K]
  __shared__ __align__(16) u16 SB[2][8192];   // rows 0-127 gate, 128-255 up
  __shared__ int toks[256];
  int tid = threadIdx.x;
  if (tid < 256) {
    int idx = row0 + tid;
    if (idx > NSLOT - 1) idx = NSLOT - 1;
    toks[tid] = perm_token[idx];
  }
  __syncthreads();
  int wave = tid >> 6, lane = tid & 63;
  int wr = wave >> 2, wc = wave & 3;
  int lr = lane & 15, lk = lane >> 4;
  int sr0 = tid >> 2;                       // rows 0..127 (+128 for 2nd load)
  int sc0 = (tid & 3) ^ ((tid >> 3) & 3);   // pre-swizzled K-chunk
  const u16* gA0 = xb + (size_t)toks[sr0] * HID + sc0 * 8;
  const u16* gA1 = xb + (size_t)toks[128 + sr0] * HID + sc0 * 8;
  const u16* wgb = wgub + (size_t)e * (2 * DFF) * HID;
  const u16* gB0 = wgb + (size_t)(n0g + sr0) * HID + sc0 * 8;          // gate row
  const u16* gB1 = wgb + (size_t)(DFF + n0g + sr0) * HID + sc0 * 8;    // up row
  int d0 = tid * 8, d1 = 4096 + tid * 8;    // linear LDS dests (u16 units)

  int slot8 = (lk ^ ((lr >> 1) & 3)) * 8;
  int abase = (wr * 128 + lr) * 32 + slot8;
  int boff0 = (wc * 32 + 0 * 16 + lr) * 32 + slot8;          // gate
  int boff1 = (wc * 32 + 1 * 16 + lr) * 32 + slot8;          // gate
  int boff2 = (128 + wc * 32 + 0 * 16 + lr) * 32 + slot8;    // up
  int boff3 = (128 + wc * 32 + 1 * 16 + lr) * 32 + slot8;    // up

  f32x4 acc[8][4];
  f32x4 zero = {0.f, 0.f, 0.f, 0.f};
#pragma unroll
  for (int m = 0; m < 8; ++m)
#pragma unroll
    for (int n = 0; n < 4; ++n) acc[m][n] = zero;

#define GU_ST(BUF, KOFF) do { \
    gload16(gA0 + (KOFF), &SA[BUF][d0]); \
    gload16(gA1 + (KOFF), &SA[BUF][d1]); \
    gload16(gB0 + (KOFF), &SB[BUF][d0]); \
    gload16(gB1 + (KOFF), &SB[BUF][d1]); } while (0)

  GU_ST(0, 0);                  // prologue: window 0 staged
  const int NW = HID / 32;      // 64 windows
  for (int w2 = 0; w2 < NW / 2; ++w2) {
    int k1 = (2 * w2 + 1) * 32;
    int k2 = (2 * w2 + 2) * 32;
    GWIN(0, GU_ST(1, k1));
    GWIN(1, if (k2 < HID) GU_ST(0, k2));
  }

  // epilogue: h = silu(g) * u ; acc[m][0,1]=gate cols, acc[m][2,3]=up cols
#pragma unroll
  for (int m = 0; m < 8; ++m)
#pragma unroll
    for (int i = 0; i < 4; ++i) {
      int row = wr * 128 + m * 16 + lk * 4 + i;
      if (row < cnt) {
#pragma unroll
        for (int nf = 0; nf < 2; ++nf) {
          int col = n0g + wc * 32 + nf * 16 + lr;
          float g = acc[m][nf][i], u = acc[m][nf + 2][i];
          float h = g / (1.f + __expf(-g)) * u;
          h_perm[(size_t)(row0 + row) * DFF + col] = f2bf(h);
        }
      }
    }
#undef GU_ST
}

// ---------------- down GEMM: 256 slots x 256 hid cols -> yp (fp16) ----------------
__global__ __launch_bounds__(512, 2) void down_fast(
    const u16* __restrict__ h_perm, const u16* __restrict__ wdb,
    const float* __restrict__ perm_w,
    const int* __restrict__ tile_e, const int* __restrict__ tile_row0,
    const int* __restrict__ tile_cnt, const int* __restrict__ tileCount,
    _Float16* __restrict__ yp) {
  int flat = blockIdx.x + blockIdx.y * 8;       // NWG = 8*288 = 2304, %8 == 0
  int xcd = flat & 7;
  int j = flat >> 3;                            // 0..287
  int tile = xcd * 36 + j / 8;
  int n0 = (j % 8) * 256;
  if (tile >= *tileCount) return;
  int e = tile_e[tile], row0 = tile_row0[tile], cnt = tile_cnt[tile];
  __shared__ __align__(16) u16 SA[2][8192];
  __shared__ __align__(16) u16 SB[2][8192];
  __shared__ float wts[256];
  int tid = threadIdx.x;
  if (tid < 256) {
    int idx = row0 + tid;
    if (idx > NSLOT - 1) idx = NSLOT - 1;
    wts[tid] = perm_w[idx];
  }
  __syncthreads();
  int wave = tid >> 6, lane = tid & 63;
  int wr = wave >> 2, wc = wave & 3;
  int lr = lane & 15, lk = lane >> 4;
  int sr0 = tid >> 2;
  int sc0 = (tid & 3) ^ ((tid >> 3) & 3);
  int ia0 = row0 + sr0;       if (ia0 > NSLOT - 1) ia0 = NSLOT - 1;
  int ia1 = row0 + 128 + sr0; if (ia1 > NSLOT - 1) ia1 = NSLOT - 1;
  const u16* gA0 = h_perm + (size_t)ia0 * DFF + sc0 * 8;
  const u16* gA1 = h_perm + (size_t)ia1 * DFF + sc0 * 8;
  const u16* wb = wdb + (size_t)e * HID * DFF;
  const u16* gB0 = wb + (size_t)(n0 + sr0) * DFF + sc0 * 8;
  const u16* gB1 = wb + (size_t)(n0 + 128 + sr0) * DFF + sc0 * 8;
  int d0 = tid * 8, d1 = 4096 + tid * 8;

  int slot8 = (lk ^ ((lr >> 1) & 3)) * 8;
  int abase = (wr * 128 + lr) * 32 + slot8;
  int boff0 = (wc * 64 + 0 * 16 + lr) * 32 + slot8;
  int boff1 = (wc * 64 + 1 * 16 + lr) * 32 + slot8;
  int boff2 = (wc * 64 + 2 * 16 + lr) * 32 + slot8;
  int boff3 = (wc * 64 + 3 * 16 + lr) * 32 + slot8;

  f32x4 acc[8][4];
  f32x4 zero = {0.f, 0.f, 0.f, 0.f};
#pragma unroll
  for (int m = 0; m < 8; ++m)
#pragma unroll
    for (int n = 0; n < 4; ++n) acc[m][n] = zero;

#define DN_ST(BUF, KOFF) do { \
    gload16(gA0 + (KOFF), &SA[BUF][d0]); \
    gload16(gA1 + (KOFF), &SA[BUF][d1]); \
    gload16(gB0 + (KOFF), &SB[BUF][d0]); \
    gload16(gB1 + (KOFF), &SB[BUF][d1]); } while (0)

  DN_ST(0, 0);
  const int NW = DFF / 32;      // 24 windows
  for (int w2 = 0; w2 < NW / 2; ++w2) {
    int k1 = (2 * w2 + 1) * 32;
    int k2 = (2 * w2 + 2) * 32;
    GWIN(0, DN_ST(1, k1));
    GWIN(1, if (k2 < DFF) DN_ST(0, k2));
  }

#pragma unroll
  for (int m = 0; m < 8; ++m)
#pragma unroll
    for (int i = 0; i < 4; ++i) {
      int row = wr * 128 + m * 16 + lk * 4 + i;
      if (row < cnt) {
        float wt = wts[row];
#pragma unroll
        for (int nf = 0; nf < 4; ++nf) {
          int col = n0 + wc * 64 + nf * 16 + lr;
          yp[(size_t)(row0 + row) * HID + col] = (_Float16)(acc[m][nf][i] * wt);
        }
      }
    }
#undef DN_ST
}

// ---------------- per-token gather-reduce of 8 slots ----------------
__global__ void reduce_kernel(const _Float16* __restrict__ yp, const int* __restrict__ inv,
                              float* __restrict__ y) {
  int t = blockIdx.x;
  __shared__ int pos[8];
  if (threadIdx.x < 8) pos[threadIdx.x] = inv[t * 8 + threadIdx.x];
  __syncthreads();
  int c = threadIdx.x * 8;
  float s[8] = {0.f, 0.f, 0.f, 0.f, 0.f, 0.f, 0.f, 0.f};
#pragma unroll
  for (int j = 0; j < 8; ++j) {
    uint4 v = *reinterpret_cast<const uint4*>(yp + (size_t)pos[j] * HID + c);
    const u16* p = reinterpret_cast<const u16*>(&v);
#pragma unroll
    for (int k = 0; k < 8; ++k) {
      _Float16 h;
      u16 us = p[k];
      __builtin_memcpy(&h, &us, 2);
      s[k] += (float)h;
    }
  }
  float* yo = y + (size_t)t * HID + c;
  float4 o0 = {s[0], s[1], s[2], s[3]};
  float4 o1 = {s[4], s[5], s[6], s[7]};
  *reinterpret_cast<float4*>(yo) = o0;
  *reinterpret_cast<float4*>(yo + 4) = o1;
}

extern "C" void kernel_launch(void* const* d_in, const int* in_sizes, int n_in,
                              void* d_out, int out_size, void* d_ws, size_t ws_size,
                              hipStream_t stream) {
  const float* x = (const float*)d_in[0];
  const float* gw = (const float*)d_in[1];
  const float* wgu = (const float*)d_in[2];
  const float* wd = (const float*)d_in[3];
  const float* sim = (const float*)d_in[4];
  float* y = (float*)d_out;

  char* ws = (char*)d_ws;
  size_t off = 0;
  auto alloc = [&](size_t bytes) {
    char* p = ws + off;
    off += (bytes + 255) & ~(size_t)255;
    return p;
  };
  u16* xb = (u16*)alloc((size_t)NTOK * HID * 2);
  u16* h_perm = (u16*)alloc((size_t)NSLOT * DFF * 2);
  int* slot_e = (int*)alloc(NSLOT * 4);
  float* slot_w = (float*)alloc(NSLOT * 4);
  int* perm_token = (int*)alloc(NSLOT * 4);
  float* perm_w = (float*)alloc(NSLOT * 4);
  int* inv = (int*)alloc(NSLOT * 4);
  int* blockCounts = (int*)alloc(NE * NB * 4);
  int* startEB = (int*)alloc(NE * NB * 4);
  int* tile_e = (int*)alloc(MAX_TILES * 4);
  int* tile_row0 = (int*)alloc(MAX_TILES * 4);
  int* tile_cnt = (int*)alloc(MAX_TILES * 4);
  int* tileCount = (int*)alloc(4);

  // bf16 weights + fp16 per-slot down output (yp aliases wgu_b region)
  size_t wgu_elems = (size_t)NE * 2 * DFF * HID;
  size_t wd_elems = (size_t)NE * HID * DFF;
  size_t region_bytes = (size_t)NSLOT * HID * 2;  // yp (268MB) > wgu_b (201MB)
  u16* wd_b = (u16*)alloc(wd_elems * 2);
  char* region = alloc(region_bytes);
  u16* wgu_b = (u16*)region;
  _Float16* yp = (_Float16*)region;
  if (off > ws_size) return;  // insufficient workspace: fail loudly

  hipMemsetAsync(blockCounts, 0, NE * NB * 4, stream);
  router_convert_kernel<<<NRB + CVT_BLOCKS, 256, 0, stream>>>(
      x, gw, sim, slot_e, slot_w, xb, blockCounts,
      wgu, wgu_b, (int)(wgu_elems / 4), wd, wd_b, (int)(wd_elems / 4));
  scan_kernel<<<1, 64, 0, stream>>>(blockCounts, startEB, tile_e, tile_row0, tile_cnt, tileCount);
  place_kernel<<<NB, 64, 0, stream>>>(slot_e, slot_w, startEB, perm_token, perm_w, inv);

  gu_fast<<<dim3(DFF / 128, MAX_TILES), 512, 0, stream>>>(
      xb, wgu_b, perm_token, tile_e, tile_row0, tile_cnt, tileCount, h_perm);
  down_fast<<<dim3(HID / 256, MAX_TILES), 512, 0, stream>>>(
      h_perm, wd_b, perm_w, tile_e, tile_row0, tile_cnt, tileCount, yp);
  reduce_kernel<<<NTOK, 256, 0, stream>>>(yp, inv, y);
}

// Round 15
// 1032.752 us; speedup vs baseline: 6.6259x; 1.0519x over previous
//
#include <hip/hip_runtime.h>
#include <stdint.h>
#include <string.h>

#define NTOK 8192
#define HID 2048
#define NE 32
#define DFF 768
#define NSLOT 65536
#define NB 256
#define MT 256
#define MAX_TILES 288   // 65536/256 + 32
#define NRB 1024        // router blocks, 8 tokens each
#define CVT_BLOCKS 4096

typedef unsigned short u16;
typedef unsigned int u32;

using f32x4 = __attribute__((ext_vector_type(4))) float;
using bf16x8 = __attribute__((ext_vector_type(8))) short;

static __device__ __forceinline__ u16 f2bf(float f) {
  u32 x = __float_as_uint(f);
  x += 0x7fffu + ((x >> 16) & 1u);
  return (u16)(x >> 16);
}

typedef const __attribute__((address_space(1))) unsigned int* gp_t;
typedef __attribute__((address_space(3))) unsigned int* lp_t;
static __device__ __forceinline__ void gload16(const void* g, void* l) {
  __builtin_amdgcn_global_load_lds((gp_t)g, (lp_t)l, 16, 0, 0);
}

// ---------------- merged: router (coalesced, x-in-regs) | weight convert ----------------
// blocks [0, NRB): router, token range [blockIdx.x*8, +8); wave w owns toks {2w, 2w+1}
// blocks [NRB, NRB+CVT_BLOCKS): grid-stride fp32->bf16 convert of wgu then wd
__global__ void router_convert_kernel(const float* __restrict__ x, const float* __restrict__ gw,
                                      const float* __restrict__ sim,
                                      int* __restrict__ slot_e, float* __restrict__ slot_w,
                                      u16* __restrict__ xb, int* __restrict__ blockCounts,
                                      const float* __restrict__ wgu, u16* __restrict__ wgu_b, int n1,
                                      const float* __restrict__ wd, u16* __restrict__ wd_b, int n2) {
  __shared__ float logits_s[8][NE];
  if (blockIdx.x >= NRB) {
    // ---- convert path ----
    int i = (blockIdx.x - NRB) * 256 + threadIdx.x;
    int stride = CVT_BLOCKS * 256;
    int total = n1 + n2;
    for (; i < total; i += stride) {
      const float* src = (i < n1) ? wgu : wd;
      u16* dst = (i < n1) ? wgu_b : wd_b;
      int k = (i < n1) ? i : (i - n1);
      float4 v = reinterpret_cast<const float4*>(src)[k];
      u32 lo = (u32)f2bf(v.x) | ((u32)f2bf(v.y) << 16);
      u32 hi = (u32)f2bf(v.z) | ((u32)f2bf(v.w) << 16);
      reinterpret_cast<uint2*>(dst)[k] = make_uint2(lo, hi);
    }
    return;
  }
  // ---- router path ----
  int tid = threadIdx.x;
  int wave = tid >> 6, lane = tid & 63;
  int tA = blockIdx.x * 8 + wave * 2;       // wave's two tokens
  int tB = tA + 1;
  const float4* xrA = reinterpret_cast<const float4*>(x + (size_t)tA * HID);
  const float4* xrB = reinterpret_cast<const float4*>(x + (size_t)tB * HID);
  float4 xa[8], xc[8];
#pragma unroll
  for (int j = 0; j < 8; ++j) { xa[j] = xrA[j * 64 + lane]; xc[j] = xrB[j * 64 + lane]; }
  // bf16 copy straight from registers (coalesced uint2 per lane)
  uint2* xoA = reinterpret_cast<uint2*>(xb + (size_t)tA * HID);
  uint2* xoB = reinterpret_cast<uint2*>(xb + (size_t)tB * HID);
#pragma unroll
  for (int j = 0; j < 8; ++j) {
    uint2 pA = make_uint2((u32)f2bf(xa[j].x) | ((u32)f2bf(xa[j].y) << 16),
                          (u32)f2bf(xa[j].z) | ((u32)f2bf(xa[j].w) << 16));
    uint2 pB = make_uint2((u32)f2bf(xc[j].x) | ((u32)f2bf(xc[j].y) << 16),
                          (u32)f2bf(xc[j].z) | ((u32)f2bf(xc[j].w) << 16));
    xoA[j * 64 + lane] = pA;
    xoB[j * 64 + lane] = pB;
  }
  // logits: loop experts, gw row coalesced, dot both register rows, butterfly-reduce
  for (int e = 0; e < NE; ++e) {
    const float4* gv = reinterpret_cast<const float4*>(gw + (size_t)e * HID);
    float aA = 0.f, aB = 0.f;
#pragma unroll
    for (int j = 0; j < 8; ++j) {
      float4 gg = gv[j * 64 + lane];
      aA = fmaf(xa[j].x, gg.x, aA); aA = fmaf(xa[j].y, gg.y, aA);
      aA = fmaf(xa[j].z, gg.z, aA); aA = fmaf(xa[j].w, gg.w, aA);
      aB = fmaf(xc[j].x, gg.x, aB); aB = fmaf(xc[j].y, gg.y, aB);
      aB = fmaf(xc[j].z, gg.z, aB); aB = fmaf(xc[j].w, gg.w, aB);
    }
#pragma unroll
    for (int off = 32; off; off >>= 1) { aA += __shfl_xor(aA, off); aB += __shfl_xor(aB, off); }
    if (lane == 0) { logits_s[wave * 2][e] = aA; logits_s[wave * 2 + 1][e] = aB; }
  }
  __syncthreads();
  // top-8 + reroute: thread (tok = tid>>5, e = tid&31), 32-lane butterfly argmax
  int tok = tid >> 5, e = tid & 31;
  float s = logits_s[tok][e];
  float cur = s;
  int myi = e;
  int idx[8]; float lv[8];
#pragma unroll
  for (int k = 0; k < 8; ++k) {
    float bv = cur; int bi = myi;
#pragma unroll
    for (int off = 16; off; off >>= 1) {
      float ov = __shfl_xor(bv, off);
      int oi = __shfl_xor(bi, off);
      if (ov > bv || (ov == bv && oi < bi)) { bv = ov; bi = oi; }
    }
    idx[k] = bi; lv[k] = bv;          // uniform across the half-wave
    if (myi == bi) cur = -3.4e38f;    // mask winner
  }
  float w[8]; float ssum = 0.f;
#pragma unroll
  for (int k = 0; k < 8; ++k) { w[k] = __expf(lv[k] - lv[0]); ssum += w[k]; }
  float inv = 1.f / ssum;
  int t = blockIdx.x * 8 + tok;
  int base = t * 8;
  if (e < 4) {
    slot_e[base + e] = idx[e];
    slot_w[base + e] = w[e] * inv;
    int sj = idx[4 + e];
    float best = -2.f; int bsel = idx[0];
#pragma unroll
    for (int i = 0; i < 4; ++i) {
      int pe = idx[i];
      float sv = sim[sj * NE + pe];
      bool ok = sv > best;              // strict > == argmax first-max
      best = ok ? sv : best;
      bsel = ok ? pe : bsel;
    }
    int ns = (best < 0.5f) ? sj : bsel;
    slot_e[base + 4 + e] = ns;
    slot_w[base + 4 + e] = w[4 + e] * inv;
    atomicAdd(&blockCounts[idx[e] * NB + (t >> 5)], 1);
    atomicAdd(&blockCounts[ns * NB + (t >> 5)], 1);
  }
}

// ---------------- counting sort: scan / place ----------------
__global__ void scan_kernel(const int* __restrict__ blockCounts, int* __restrict__ startEB,
                            int* __restrict__ tile_e, int* __restrict__ tile_row0,
                            int* __restrict__ tile_cnt, int* __restrict__ tileCount) {
  __shared__ int totals[NE];
  __shared__ int bases[NE];
  int t = threadIdx.x;
  if (t < NE) {
    int run = 0;
    for (int b = 0; b < NB; ++b) run += blockCounts[t * NB + b];
    totals[t] = run;
  }
  __syncthreads();
  if (t == 0) {
    int base = 0, nt = 0;
    for (int e = 0; e < NE; ++e) {
      bases[e] = base;
      int tot = totals[e];
      for (int i = 0; i < tot; i += MT) {
        tile_e[nt] = e;
        tile_row0[nt] = base + i;
        tile_cnt[nt] = (tot - i < MT) ? (tot - i) : MT;
        ++nt;
      }
      base += tot;
    }
    *tileCount = nt;
  }
  __syncthreads();
  if (t < NE) {
    int run = bases[t];
    for (int b = 0; b < NB; ++b) {
      startEB[t * NB + b] = run;
      run += blockCounts[t * NB + b];
    }
  }
}

__global__ void place_kernel(const int* __restrict__ slot_e, const float* __restrict__ slot_w,
                             const int* __restrict__ startEB,
                             int* __restrict__ perm_token, float* __restrict__ perm_w,
                             int* __restrict__ inv) {
  __shared__ int se[256];
  __shared__ float sw[256];
  int b = blockIdx.x;
  for (int i = threadIdx.x; i < 256; i += 64) {
    se[i] = slot_e[b * 256 + i];
    sw[i] = slot_w[b * 256 + i];
  }
  __syncthreads();
  int e = threadIdx.x;
  if (e < NE) {
    int pos = startEB[e * NB + b];
    for (int i = 0; i < 256; ++i) {
      if (se[i] == e) {
        perm_token[pos] = (b * 256 + i) >> 3;
        perm_w[pos] = sw[i];
        inv[b * 256 + i] = pos;
        ++pos;
      }
    }
  }
}

// ---------------- 4-window 256x256 grouped GEMM machinery (round-12 optimum) ----------------
// One window per (buf,kk) region: lgkm-drain + vmcnt(N) + single barrier, then two
// 16-MFMA sub-phases with free compiler scheduling. vmcnt(8) steady, 8/8/4/0 tail.

#define GUMM(AR, M_)                                                                   \
  acc[M_][0] = __builtin_amdgcn_mfma_f32_16x16x32_bf16(AR, b0, acc[M_][0], 0, 0, 0);   \
  acc[M_][1] = __builtin_amdgcn_mfma_f32_16x16x32_bf16(AR, b1, acc[M_][1], 0, 0, 0);   \
  acc[M_][2] = __builtin_amdgcn_mfma_f32_16x16x32_bf16(AR, b2, acc[M_][2], 0, 0, 0);   \
  acc[M_][3] = __builtin_amdgcn_mfma_f32_16x16x32_bf16(AR, b3, acc[M_][3], 0, 0, 0);

#define GWIN(BUF, KK, VM, S1, S2)                                                      \
  do {                                                                                 \
    asm volatile("s_waitcnt lgkmcnt(0)" ::: "memory");                                 \
    __builtin_amdgcn_sched_barrier(0);                                                 \
    asm volatile("s_waitcnt vmcnt(" #VM ")" ::: "memory");                             \
    __builtin_amdgcn_s_barrier();                                                      \
    const u16* Ap_ = &SA[BUF][KK][abase];                                              \
    const u16* Bp_ = &SB[BUF][KK][0];                                                  \
    bf16x8 a0_ = *(const bf16x8*)(Ap_);                                                \
    bf16x8 a1_ = *(const bf16x8*)(Ap_ + 512);                                          \
    bf16x8 a2_ = *(const bf16x8*)(Ap_ + 1024);                                         \
    bf16x8 a3_ = *(const bf16x8*)(Ap_ + 1536);                                         \
    bf16x8 b0 = *(const bf16x8*)(Bp_ + boff0);                                         \
    bf16x8 b1 = *(const bf16x8*)(Bp_ + boff1);                                         \
    bf16x8 b2 = *(const bf16x8*)(Bp_ + boff2);                                         \
    bf16x8 b3 = *(const bf16x8*)(Bp_ + boff3);                                         \
    S1;                                                                                \
    __builtin_amdgcn_s_setprio(1);                                                     \
    GUMM(a0_, 0) GUMM(a1_, 1) GUMM(a2_, 2) GUMM(a3_, 3)                                \
    __builtin_amdgcn_s_setprio(0);                                                     \
    bf16x8 c0_ = *(const bf16x8*)(Ap_ + 2048);                                         \
    bf16x8 c1_ = *(const bf16x8*)(Ap_ + 2560);                                         \
    bf16x8 c2_ = *(const bf16x8*)(Ap_ + 3072);                                         \
    bf16x8 c3_ = *(const bf16x8*)(Ap_ + 3584);                                         \
    S2;                                                                                \
    __builtin_amdgcn_s_setprio(1);                                                     \
    GUMM(c0_, 4) GUMM(c1_, 5) GUMM(c2_, 6) GUMM(c3_, 7)                                \
    __builtin_amdgcn_s_setprio(0);                                                     \
  } while (0)

// ---------------- gate_up GEMM: 256 slots x (128 gate + 128 up cols) ----------------
__global__ __launch_bounds__(512, 2) void gu_fast(
    const u16* __restrict__ xb, const u16* __restrict__ wgub,
    const int* __restrict__ perm_token,
    const int* __restrict__ tile_e, const int* __restrict__ tile_row0,
    const int* __restrict__ tile_cnt, const int* __restrict__ tileCount,
    u16* __restrict__ h_perm) {
  // XCD clustering: flat%8 = XCD; give each XCD a contiguous 36-tile chunk.
  int flat = blockIdx.x + blockIdx.y * 6;       // NWG = 6*288 = 1728, %8 == 0
  int xcd = flat & 7;
  int j = flat >> 3;                            // 0..215
  int tile = xcd * 36 + j / 6;
  int n0g = (j % 6) * 128;
  if (tile >= *tileCount) return;
  int e = tile_e[tile], row0 = tile_row0[tile], cnt = tile_cnt[tile];
  __shared__ __align__(16) u16 SA[2][2][8192];   // [buf][kk][256 rows x 32 K]
  __shared__ __align__(16) u16 SB[2][2][8192];   // rows 0-127 gate, 128-255 up
  __shared__ int toks[256];
  int tid = threadIdx.x;
  if (tid < 256) {
    int idx = row0 + tid;
    if (idx > NSLOT - 1) idx = NSLOT - 1;
    toks[tid] = perm_token[idx];
  }
  __syncthreads();
  int wave = tid >> 6, lane = tid & 63;
  int wr = wave >> 2, wc = wave & 3;
  int lr = lane & 15, lk = lane >> 4;
  int sr0 = tid >> 2;                       // rows 0..127 (+128 for 2nd load)
  int sc0 = (tid & 3) ^ ((tid >> 3) & 3);   // pre-swizzled K-chunk
  const u16* gA0 = xb + (size_t)toks[sr0] * HID + sc0 * 8;
  const u16* gA1 = xb + (size_t)toks[128 + sr0] * HID + sc0 * 8;
  const u16* wgb = wgub + (size_t)e * (2 * DFF) * HID;
  const u16* gB0 = wgb + (size_t)(n0g + sr0) * HID + sc0 * 8;          // gate row
  const u16* gB1 = wgb + (size_t)(DFF + n0g + sr0) * HID + sc0 * 8;    // up row
  int d0 = tid * 8, d1 = 4096 + tid * 8;    // linear LDS dests (u16 units)

  int slot8 = (lk ^ ((lr >> 1) & 3)) * 8;
  int abase = (wr * 128 + lr) * 32 + slot8;
  int boff0 = (wc * 32 + 0 * 16 + lr) * 32 + slot8;          // gate
  int boff1 = (wc * 32 + 1 * 16 + lr) * 32 + slot8;          // gate
  int boff2 = (128 + wc * 32 + 0 * 16 + lr) * 32 + slot8;    // up
  int boff3 = (128 + wc * 32 + 1 * 16 + lr) * 32 + slot8;    // up

  f32x4 acc[8][4];
  f32x4 zero = {0.f, 0.f, 0.f, 0.f};
#pragma unroll
  for (int m = 0; m < 8; ++m)
#pragma unroll
    for (int n = 0; n < 4; ++n) acc[m][n] = zero;

#define GU_SGA(BUF, KK, KT) do { \
    gload16(gA0 + (KT) + (KK) * 32, &SA[BUF][KK][d0]); \
    gload16(gA1 + (KT) + (KK) * 32, &SA[BUF][KK][d1]); } while (0)
#define GU_SGB(BUF, KK, KT) do { \
    gload16(gB0 + (KT) + (KK) * 32, &SB[BUF][KK][d0]); \
    gload16(gB1 + (KT) + (KK) * 32, &SB[BUF][KK][d1]); } while (0)

  // prologue: t0 full (buf0), t1.kk0 (buf1) = 12 loads in flight
  GU_SGA(0, 0, 0); GU_SGB(0, 0, 0);
  GU_SGA(0, 1, 0); GU_SGB(0, 1, 0);
  GU_SGA(1, 0, 64); GU_SGB(1, 0, 64);

  const int NKT = HID / 64;   // 32
  const int NI = NKT / 2;     // 16
  for (int it = 0; it < NI - 1; ++it) {
    int ktA = (2 * it + 1) * 64;
    int ktB = (2 * it + 2) * 64;
    int ktC = (2 * it + 3) * 64;
    GWIN(0, 0, 8, GU_SGA(1, 1, ktA), GU_SGB(1, 1, ktA));
    GWIN(0, 1, 8, GU_SGA(0, 0, ktB), GU_SGB(0, 0, ktB));
    GWIN(1, 0, 8, GU_SGA(0, 1, ktB), GU_SGB(0, 1, ktB));
    GWIN(1, 1, 8, GU_SGA(1, 0, ktC), GU_SGB(1, 0, ktC));
  }
  {
    int ktA = (2 * (NI - 1) + 1) * 64;
    GWIN(0, 0, 8, GU_SGA(1, 1, ktA), GU_SGB(1, 1, ktA));
    GWIN(0, 1, 8, (void)0, (void)0);
    GWIN(1, 0, 4, (void)0, (void)0);
    GWIN(1, 1, 0, (void)0, (void)0);
  }

  // epilogue: h = silu(g) * u ; acc[m][0,1]=gate cols, acc[m][2,3]=up cols
#pragma unroll
  for (int m = 0; m < 8; ++m)
#pragma unroll
    for (int i = 0; i < 4; ++i) {
      int row = wr * 128 + m * 16 + lk * 4 + i;
      if (row < cnt) {
#pragma unroll
        for (int nf = 0; nf < 2; ++nf) {
          int col = n0g + wc * 32 + nf * 16 + lr;
          float g = acc[m][nf][i], u = acc[m][nf + 2][i];
          float h = g / (1.f + __expf(-g)) * u;
          h_perm[(size_t)(row0 + row) * DFF + col] = f2bf(h);
        }
      }
    }
#undef GU_SGA
#undef GU_SGB
}

// ---------------- down GEMM: 256 slots x 256 hid cols -> yp (fp16) ----------------
__global__ __launch_bounds__(512, 2) void down_fast(
    const u16* __restrict__ h_perm, const u16* __restrict__ wdb,
    const float* __restrict__ perm_w,
    const int* __restrict__ tile_e, const int* __restrict__ tile_row0,
    const int* __restrict__ tile_cnt, const int* __restrict__ tileCount,
    _Float16* __restrict__ yp) {
  int flat = blockIdx.x + blockIdx.y * 8;       // NWG = 8*288 = 2304, %8 == 0
  int xcd = flat & 7;
  int j = flat >> 3;                            // 0..287
  int tile = xcd * 36 + j / 8;
  int n0 = (j % 8) * 256;
  if (tile >= *tileCount) return;
  int e = tile_e[tile], row0 = tile_row0[tile], cnt = tile_cnt[tile];
  __shared__ __align__(16) u16 SA[2][2][8192];
  __shared__ __align__(16) u16 SB[2][2][8192];
  __shared__ float wts[256];
  int tid = threadIdx.x;
  if (tid < 256) {
    int idx = row0 + tid;
    if (idx > NSLOT - 1) idx = NSLOT - 1;
    wts[tid] = perm_w[idx];
  }
  __syncthreads();
  int wave = tid >> 6, lane = tid & 63;
  int wr = wave >> 2, wc = wave & 3;
  int lr = lane & 15, lk = lane >> 4;
  int sr0 = tid >> 2;
  int sc0 = (tid & 3) ^ ((tid >> 3) & 3);
  int ia0 = row0 + sr0;       if (ia0 > NSLOT - 1) ia0 = NSLOT - 1;
  int ia1 = row0 + 128 + sr0; if (ia1 > NSLOT - 1) ia1 = NSLOT - 1;
  const u16* gA0 = h_perm + (size_t)ia0 * DFF + sc0 * 8;
  const u16* gA1 = h_perm + (size_t)ia1 * DFF + sc0 * 8;
  const u16* wb = wdb + (size_t)e * HID * DFF;
  const u16* gB0 = wb + (size_t)(n0 + sr0) * DFF + sc0 * 8;
  const u16* gB1 = wb + (size_t)(n0 + 128 + sr0) * DFF + sc0 * 8;
  int d0 = tid * 8, d1 = 4096 + tid * 8;

  int slot8 = (lk ^ ((lr >> 1) & 3)) * 8;
  int abase = (wr * 128 + lr) * 32 + slot8;
  int boff0 = (wc * 64 + 0 * 16 + lr) * 32 + slot8;
  int boff1 = (wc * 64 + 1 * 16 + lr) * 32 + slot8;
  int boff2 = (wc * 64 + 2 * 16 + lr) * 32 + slot8;
  int boff3 = (wc * 64 + 3 * 16 + lr) * 32 + slot8;

  f32x4 acc[8][4];
  f32x4 zero = {0.f, 0.f, 0.f, 0.f};
#pragma unroll
  for (int m = 0; m < 8; ++m)
#pragma unroll
    for (int n = 0; n < 4; ++n) acc[m][n] = zero;

#define DN_SGA(BUF, KK, KT) do { \
    gload16(gA0 + (KT) + (KK) * 32, &SA[BUF][KK][d0]); \
    gload16(gA1 + (KT) + (KK) * 32, &SA[BUF][KK][d1]); } while (0)
#define DN_SGB(BUF, KK, KT) do { \
    gload16(gB0 + (KT) + (KK) * 32, &SB[BUF][KK][d0]); \
    gload16(gB1 + (KT) + (KK) * 32, &SB[BUF][KK][d1]); } while (0)

  DN_SGA(0, 0, 0); DN_SGB(0, 0, 0);
  DN_SGA(0, 1, 0); DN_SGB(0, 1, 0);
  DN_SGA(1, 0, 64); DN_SGB(1, 0, 64);

  const int NKT = DFF / 64;   // 12
  const int NI = NKT / 2;     // 6
  for (int it = 0; it < NI - 1; ++it) {
    int ktA = (2 * it + 1) * 64;
    int ktB = (2 * it + 2) * 64;
    int ktC = (2 * it + 3) * 64;
    GWIN(0, 0, 8, DN_SGA(1, 1, ktA), DN_SGB(1, 1, ktA));
    GWIN(0, 1, 8, DN_SGA(0, 0, ktB), DN_SGB(0, 0, ktB));
    GWIN(1, 0, 8, DN_SGA(0, 1, ktB), DN_SGB(0, 1, ktB));
    GWIN(1, 1, 8, DN_SGA(1, 0, ktC), DN_SGB(1, 0, ktC));
  }
  {
    int ktA = (2 * (NI - 1) + 1) * 64;
    GWIN(0, 0, 8, DN_SGA(1, 1, ktA), DN_SGB(1, 1, ktA));
    GWIN(0, 1, 8, (void)0, (void)0);
    GWIN(1, 0, 4, (void)0, (void)0);
    GWIN(1, 1, 0, (void)0, (void)0);
  }

#pragma unroll
  for (int m = 0; m < 8; ++m)
#pragma unroll
    for (int i = 0; i < 4; ++i) {
      int row = wr * 128 + m * 16 + lk * 4 + i;
      if (row < cnt) {
        float wt = wts[row];
#pragma unroll
        for (int nf = 0; nf < 4; ++nf) {
          int col = n0 + wc * 64 + nf * 16 + lr;
          yp[(size_t)(row0 + row) * HID + col] = (_Float16)(acc[m][nf][i] * wt);
        }
      }
    }
#undef DN_SGA
#undef DN_SGB
}

// ---------------- per-token gather-reduce of 8 slots ----------------
__global__ void reduce_kernel(const _Float16* __restrict__ yp, const int* __restrict__ inv,
                              float* __restrict__ y) {
  int t = blockIdx.x;
  __shared__ int pos[8];
  if (threadIdx.x < 8) pos[threadIdx.x] = inv[t * 8 + threadIdx.x];
  __syncthreads();
  int c = threadIdx.x * 8;
  float s[8] = {0.f, 0.f, 0.f, 0.f, 0.f, 0.f, 0.f, 0.f};
#pragma unroll
  for (int j = 0; j < 8; ++j) {
    uint4 v = *reinterpret_cast<const uint4*>(yp + (size_t)pos[j] * HID + c);
    const u16* p = reinterpret_cast<const u16*>(&v);
#pragma unroll
    for (int k = 0; k < 8; ++k) {
      _Float16 h;
      u16 us = p[k];
      __builtin_memcpy(&h, &us, 2);
      s[k] += (float)h;
    }
  }
  float* yo = y + (size_t)t * HID + c;
  float4 o0 = {s[0], s[1], s[2], s[3]};
  float4 o1 = {s[4], s[5], s[6], s[7]};
  *reinterpret_cast<float4*>(yo) = o0;
  *reinterpret_cast<float4*>(yo + 4) = o1;
}

extern "C" void kernel_launch(void* const* d_in, const int* in_sizes, int n_in,
                              void* d_out, int out_size, void* d_ws, size_t ws_size,
                              hipStream_t stream) {
  const float* x = (const float*)d_in[0];
  const float* gw = (const float*)d_in[1];
  const float* wgu = (const float*)d_in[2];
  const float* wd = (const float*)d_in[3];
  const float* sim = (const float*)d_in[4];
  float* y = (float*)d_out;

  char* ws = (char*)d_ws;
  size_t off = 0;
  auto alloc = [&](size_t bytes) {
    char* p = ws + off;
    off += (bytes + 255) & ~(size_t)255;
    return p;
  };
  u16* xb = (u16*)alloc((size_t)NTOK * HID * 2);
  u16* h_perm = (u16*)alloc((size_t)NSLOT * DFF * 2);
  int* slot_e = (int*)alloc(NSLOT * 4);
  float* slot_w = (float*)alloc(NSLOT * 4);
  int* perm_token = (int*)alloc(NSLOT * 4);
  float* perm_w = (float*)alloc(NSLOT * 4);
  int* inv = (int*)alloc(NSLOT * 4);
  int* blockCounts = (int*)alloc(NE * NB * 4);
  int* startEB = (int*)alloc(NE * NB * 4);
  int* tile_e = (int*)alloc(MAX_TILES * 4);
  int* tile_row0 = (int*)alloc(MAX_TILES * 4);
  int* tile_cnt = (int*)alloc(MAX_TILES * 4);
  int* tileCount = (int*)alloc(4);

  // bf16 weights + fp16 per-slot down output (yp aliases wgu_b region)
  size_t wgu_elems = (size_t)NE * 2 * DFF * HID;
  size_t wd_elems = (size_t)NE * HID * DFF;
  size_t region_bytes = (size_t)NSLOT * HID * 2;  // yp (268MB) > wgu_b (201MB)
  u16* wd_b = (u16*)alloc(wd_elems * 2);
  char* region = alloc(region_bytes);
  u16* wgu_b = (u16*)region;
  _Float16* yp = (_Float16*)region;
  if (off > ws_size) return;  // insufficient workspace: fail loudly

  hipMemsetAsync(blockCounts, 0, NE * NB * 4, stream);
  router_convert_kernel<<<NRB + CVT_BLOCKS, 256, 0, stream>>>(
      x, gw, sim, slot_e, slot_w, xb, blockCounts,
      wgu, wgu_b, (int)(wgu_elems / 4), wd, wd_b, (int)(wd_elems / 4));
  scan_kernel<<<1, 64, 0, stream>>>(blockCounts, startEB, tile_e, tile_row0, tile_cnt, tileCount);
  place_kernel<<<NB, 64, 0, stream>>>(slot_e, slot_w, startEB, perm_token, perm_w, inv);

  gu_fast<<<dim3(DFF / 128, MAX_TILES), 512, 0, stream>>>(
      xb, wgu_b, perm_token, tile_e, tile_row0, tile_cnt, tileCount, h_perm);
  down_fast<<<dim3(HID / 256, MAX_TILES), 512, 0, stream>>>(
      h_perm, wd_b, perm_w, tile_e, tile_row0, tile_cnt, tileCount, yp);
  reduce_kernel<<<NTOK, 256, 0, stream>>>(yp, inv, y);
}